// Round 7
// baseline (601.246 us; speedup 1.0000x reference)
//
#include <hip/hip_runtime.h>
#include <hip/hip_bf16.h>

typedef unsigned int u32;
typedef unsigned short u16;
typedef __attribute__((ext_vector_type(8))) short short8;
typedef __attribute__((ext_vector_type(4))) float floatx4;

#define COUT 128
#define GSEG 30000
#define BN_EPS 1e-3f
#define REP 32            // stat-accumulator replicas (kills same-address atomic serialization)

__device__ __forceinline__ u32 f2bf(float x) {
    u32 u = __float_as_uint(x);
    return (u + 0x7fffu + ((u >> 16) & 1u)) >> 16;   // RNE bf16
}
__device__ __forceinline__ float bf2f(u32 b) { return __uint_as_float(b << 16); }

__device__ __forceinline__ void unpack8(uint4 v, float* f) {
    f[0] = __uint_as_float(v.x << 16); f[1] = __uint_as_float(v.x & 0xffff0000u);
    f[2] = __uint_as_float(v.y << 16); f[3] = __uint_as_float(v.y & 0xffff0000u);
    f[4] = __uint_as_float(v.z << 16); f[5] = __uint_as_float(v.z & 0xffff0000u);
    f[6] = __uint_as_float(v.w << 16); f[7] = __uint_as_float(v.w & 0xffff0000u);
}

__device__ __forceinline__ float agent_ld(const float* p) {
    return __hip_atomic_load(p, __ATOMIC_RELAXED, __HIP_MEMORY_SCOPE_AGENT);
}

// ---------------- prep: block0 converts W to fragment order; blocks 1-7 zero ---
__global__ __launch_bounds__(512) void k_prep(
    const float* __restrict__ W, u16* __restrict__ wt_f,
    u32* __restrict__ zero_base, int* __restrict__ cnt)
{
    int t = threadIdx.x;
    if (blockIdx.x == 0) {
        for (int f = t; f < 8192; f += 512) {
            int ch = f >> 3, e = f & 7;
            int ct = ch >> 7, ks = (ch >> 6) & 1, lane = ch & 63;
            int c = ct * 16 + (lane & 15);
            int k = ks * 32 + (lane >> 4) * 8 + e;
            float w = W[k * 128 + c];
            u32 hb = f2bf(w);
            float lo = w - bf2f(hb);
            wt_f[f] = (u16)hb;
            wt_f[8192 + f] = (u16)f2bf(lo);
        }
    } else {
        int tid = (blockIdx.x - 1) * 512 + t;          // 0..3583
        for (int i = tid; i < 16900; i += 3584) zero_base[i] = 0;   // stats+done [0,67600)
        for (int i = tid; i < GSEG; i += 3584) cnt[i] = 0;
    }
}

// ---------------- K1: lin = A @ W + b (split-bf16 MFMA) + BN1 stats + hist ----
// 512 thr (8 waves), 512 rows/block, 4 pipelined iterations, W staged once.
// Last block (device ticket) computes scale1/shift1 (fin fused).
__global__ __launch_bounds__(512) void k_gemm_bn1(
    const float* __restrict__ A, const u16* __restrict__ wt_f,
    const float* __restrict__ bias, const int* __restrict__ unq, int* __restrict__ cnt,
    u16* __restrict__ lin, float* __restrict__ sum1rep, float* __restrict__ sumsq1rep,
    const float* __restrict__ g1, const float* __restrict__ be1,
    float* __restrict__ scale1, float* __restrict__ shift1,
    int* __restrict__ done1, float inv_n, int n)
{
    __shared__ u16 smw[16384];   // fragment-order W: hi [0,8192), lo [8192,16384)
    __shared__ float sSum[128], sSq[128];
    __shared__ int sLast;

    const int t = threadIdx.x;
    const int base = blockIdx.x * 512;
    if (t < 128) { sSum[t] = 0.f; sSq[t] = 0.f; }

    // fused histogram: one row per thread (512 rows/block)
    if (base + t < n) atomicAdd(&cnt[unq[base + t]], 1);

    const int lane = t & 63, wv = t >> 6;
    const int r = lane & 15, q = lane >> 4;
    const int rw0 = wv * 16;

    // stage W to LDS: 2048 coalesced 16B chunks (conflict-free)
#pragma unroll
    for (int j = 0; j < 4; j++) {
        int chunk = j * 512 + t;
        *(uint4*)&smw[chunk * 8] = *(const uint4*)(wt_f + chunk * 8);
    }

    // prime iter-0 A fragments
    float4 av[2][4];
    {
        int row_a = base + rw0 + r;
        const float* ap = A + (size_t)row_a * 64;
        bool ok = row_a < n;
#pragma unroll
        for (int ks = 0; ks < 2; ks++) {
            av[0][ks * 2]     = ok ? *(const float4*)(ap + ks * 32 + q * 8)     : make_float4(0.f, 0.f, 0.f, 0.f);
            av[0][ks * 2 + 1] = ok ? *(const float4*)(ap + ks * 32 + q * 8 + 4) : make_float4(0.f, 0.f, 0.f, 0.f);
        }
    }
    __syncthreads();   // W staged; sSum/sSq init visible

    float bv[8];
#pragma unroll
    for (int ct = 0; ct < 8; ct++) bv[ct] = bias[ct * 16 + r];

    float ssum[8], ssq[8];
#pragma unroll
    for (int ct = 0; ct < 8; ct++) { ssum[ct] = 0.f; ssq[ct] = 0.f; }

    const int fbase = lane * 8;

#pragma unroll
    for (int it = 0; it < 4; it++) {
        const int cur = it & 1, nxt = cur ^ 1;
        if (it < 3) {
            int row_n = base + (it + 1) * 128 + rw0 + r;
            const float* ap = A + (size_t)row_n * 64;
            bool ok = row_n < n;
#pragma unroll
            for (int ks = 0; ks < 2; ks++) {
                av[nxt][ks * 2]     = ok ? *(const float4*)(ap + ks * 32 + q * 8)     : make_float4(0.f, 0.f, 0.f, 0.f);
                av[nxt][ks * 2 + 1] = ok ? *(const float4*)(ap + ks * 32 + q * 8 + 4) : make_float4(0.f, 0.f, 0.f, 0.f);
            }
        }
        short8 arh[2], arl[2];
#pragma unroll
        for (int ks = 0; ks < 2; ks++) {
            float vv[8] = {av[cur][ks * 2].x, av[cur][ks * 2].y, av[cur][ks * 2].z, av[cur][ks * 2].w,
                           av[cur][ks * 2 + 1].x, av[cur][ks * 2 + 1].y, av[cur][ks * 2 + 1].z, av[cur][ks * 2 + 1].w};
#pragma unroll
            for (int i = 0; i < 8; i++) {
                u32 hb = f2bf(vv[i]);
                float lo = vv[i] - bf2f(hb);
                arh[ks][i] = (short)(u16)hb;
                arl[ks][i] = (short)(u16)f2bf(lo);
            }
        }

        floatx4 acc[8];
#pragma unroll
        for (int ct = 0; ct < 8; ct++) acc[ct] = (floatx4){0.f, 0.f, 0.f, 0.f};

#pragma unroll
        for (int ct = 0; ct < 8; ct++) {
#pragma unroll
            for (int ks = 0; ks < 2; ks++) {
                int fo = (ct * 2 + ks) * 512 + fbase;
                short8 wh = *(const short8*)&smw[fo];
                short8 wl = *(const short8*)&smw[8192 + fo];
                acc[ct] = __builtin_amdgcn_mfma_f32_16x16x32_bf16(arh[ks], wh, acc[ct], 0, 0, 0);
                acc[ct] = __builtin_amdgcn_mfma_f32_16x16x32_bf16(arl[ks], wh, acc[ct], 0, 0, 0);
                acc[ct] = __builtin_amdgcn_mfma_f32_16x16x32_bf16(arh[ks], wl, acc[ct], 0, 0, 0);
            }
        }

#pragma unroll
        for (int ct = 0; ct < 8; ct++) {
            int c = ct * 16 + r;
#pragma unroll
            for (int i = 0; i < 4; i++) {
                int grow = base + it * 128 + rw0 + q * 4 + i;
                float v = acc[ct][i] + bv[ct];
                if (grow < n) {
                    ssum[ct] += v; ssq[ct] += v * v;
                    lin[(size_t)grow * 128 + c] = (u16)f2bf(v);
                }
            }
        }
    }

    // stats: wave reduce -> LDS -> one replicated global atomic round
#pragma unroll
    for (int ct = 0; ct < 8; ct++) {
        float s = ssum[ct], qq = ssq[ct];
        s += __shfl_xor(s, 16, 64); qq += __shfl_xor(qq, 16, 64);
        s += __shfl_xor(s, 32, 64); qq += __shfl_xor(qq, 32, 64);
        if (lane < 16) { atomicAdd(&sSum[ct * 16 + r], s); atomicAdd(&sSq[ct * 16 + r], qq); }
    }
    __syncthreads();
    if (t < 128) {
        int rep = (blockIdx.x & (REP - 1)) * 128;
        atomicAdd(&sum1rep[rep + t], sSum[t]);
        atomicAdd(&sumsq1rep[rep + t], sSq[t]);
    }
    __syncthreads();   // drains all waves' atomics (vmcnt at barrier)
    if (t == 0) {
        __threadfence();
        sLast = (atomicAdd(done1, 1) == (int)gridDim.x - 1);
    }
    __syncthreads();
    if (sLast && t < 128) {      // fused BN1 finalize (last block only)
        float s = 0.f, qq = 0.f;
#pragma unroll
        for (int rr = 0; rr < REP; rr++) {
            s  += agent_ld(&sum1rep[rr * 128 + t]);
            qq += agent_ld(&sumsq1rep[rr * 128 + t]);
        }
        float mean = s * inv_n;
        float var = qq * inv_n - mean * mean;
        float sc = g1[t] * rsqrtf(var + BN_EPS);
        scale1[t] = sc;
        shift1[t] = be1[t] - mean * sc;
    }
}

// ---------------- K2b: single-pass exclusive scan (1024 thr x 32 elems) -------
__global__ __launch_bounds__(1024) void k_scan(const int* __restrict__ cnt,
                                               int* __restrict__ offs,
                                               int* __restrict__ cursor)
{
    __shared__ int wsum[16];
    int t = threadIdx.x, lane = t & 63, wv = t >> 6;
    int base = t * 32;
    int v[32];
    int s = 0;
    if (base + 32 <= GSEG) {
        const int4* cp = (const int4*)(cnt + base);
#pragma unroll
        for (int j = 0; j < 8; j++) {
            int4 q = cp[j];
            v[j * 4 + 0] = q.x; v[j * 4 + 1] = q.y; v[j * 4 + 2] = q.z; v[j * 4 + 3] = q.w;
            s += q.x + q.y + q.z + q.w;
        }
    } else {
#pragma unroll
        for (int j = 0; j < 32; j++) {
            int idx = base + j;
            int x = (idx < GSEG) ? cnt[idx] : 0;
            v[j] = x; s += x;
        }
    }
    int x = s;
#pragma unroll
    for (int d = 1; d < 64; d <<= 1) {
        int u = __shfl_up(x, d, 64);
        if (lane >= d) x += u;
    }
    if (lane == 63) wsum[wv] = x;
    __syncthreads();
    if (t < 16) {
        int w = wsum[t];
#pragma unroll
        for (int d = 1; d < 16; d <<= 1) {
            int u = __shfl_up(w, d, 16);
            if (t >= d) w += u;
        }
        wsum[t] = w;
    }
    __syncthreads();
    int run = (wv ? wsum[wv - 1] : 0) + (x - s);
#pragma unroll
    for (int j = 0; j < 32; j++) {
        int idx = base + j;
        if (idx < GSEG) { offs[idx] = run; cursor[idx] = run; }
        run += v[j];
    }
    if (t == 1023) offs[GSEG] = wsum[15];
}

// ---------------- K2c: scatter row indices into segment-sorted order -----------
__global__ __launch_bounds__(256) void k_scatter_idx(const int* __restrict__ unq,
                                                     int* __restrict__ cursor,
                                                     int* __restrict__ order, int n)
{
    int i = blockIdx.x * 256 + threadIdx.x;
    if (i < n) {
        int pos = atomicAdd(&cursor[unq[i]], 1);
        order[pos] = i;
    }
}

// ---------------- K2d: per-segment gather sum + fused BN2 raw moments ----------
// Last block (ticket) computes scale2/shift2 (fin fused).
__global__ __launch_bounds__(256) void k_segsum(
    const u16* __restrict__ lin, const float* __restrict__ xyz,
    const int* __restrict__ order, const int* __restrict__ offs,
    const float* __restrict__ scale1, const float* __restrict__ shift1,
    const float* __restrict__ Wp1, const float* __restrict__ bp1,
    const float* __restrict__ Wp2, const float* __restrict__ bp2,
    float* __restrict__ feat_add, float* __restrict__ sum2rep, float* __restrict__ sumsq2rep,
    const float* __restrict__ g2, const float* __restrict__ be2,
    float* __restrict__ scale2, float* __restrict__ shift2,
    int* __restrict__ done2, float inv_n, int nseg)
{
    __shared__ float sSum[128], sSq[128];
    __shared__ int sLast;
    const int t = threadIdx.x;
    if (t < 128) { sSum[t] = 0.f; sSq[t] = 0.f; }
    __syncthreads();
    const int wave = t >> 6, lane = t & 63;
    const int c = lane * 2;
    const float wa0x = Wp1[c],     wa0y = Wp1[128 + c],     wa0z = Wp1[256 + c],     ba0 = bp1[c];
    const float wa1x = Wp1[c + 1], wa1y = Wp1[128 + c + 1], wa1z = Wp1[256 + c + 1], ba1 = bp1[c + 1];
    const float wb0x = Wp2[c],     wb0y = Wp2[128 + c],     wb0z = Wp2[256 + c],     bb0 = bp2[c];
    const float wb1x = Wp2[c + 1], wb1y = Wp2[128 + c + 1], wb1z = Wp2[256 + c + 1], bb1 = bp2[c + 1];
    const float sc0 = scale1[c], sh0 = shift1[c];
    const float sc1 = scale1[c + 1], sh1 = shift1[c + 1];
    float rs0 = 0.f, rs1 = 0.f, rq0 = 0.f, rq1 = 0.f;
    const int stride = gridDim.x * 4;
    for (int s = blockIdx.x * 4 + wave; s < nseg; s += stride) {
        const int beg = offs[s], end = offs[s + 1];
        const int m = end - beg;
        int rowv = 0; float fxv = 0.f, fyv = 0.f, fzv = 0.f;
        if (lane < m) {
            rowv = order[beg + lane];
            float2 xy = *(const float2*)(xyz + rowv * 3);
            fxv = floorf(xy.x);
            fyv = floorf(xy.y);
            fzv = floorf(xyz[rowv * 3 + 2]);
        }
        float acc0 = 0.f, acc1 = 0.f, p10 = 0.f, p11 = 0.f, p20 = 0.f, p21 = 0.f;
        const int mm = m < 64 ? m : 64;
        int j = 0;
        for (; j + 4 <= mm; j += 4) {
            int   rw[4]; float px[4], py[4], pz[4]; u32 ll[4];
#pragma unroll
            for (int k = 0; k < 4; k++) {
                rw[k] = __shfl(rowv, j + k, 64);
                px[k] = __shfl(fxv, j + k, 64);
                py[k] = __shfl(fyv, j + k, 64);
                pz[k] = __shfl(fzv, j + k, 64);
            }
#pragma unroll
            for (int k = 0; k < 4; k++)
                ll[k] = *(const u32*)(lin + (size_t)rw[k] * 128 + c);
#pragma unroll
            for (int k = 0; k < 4; k++) {
                float fe0 = fmaf(__uint_as_float(ll[k] << 16), sc0, sh0);
                float fe1 = fmaf(__uint_as_float(ll[k] & 0xffff0000u), sc1, sh1);
                float pa0 = fmaf(px[k], wa0x, fmaf(py[k], wa0y, fmaf(pz[k], wa0z, ba0)));
                float pa1 = fmaf(px[k], wa1x, fmaf(py[k], wa1y, fmaf(pz[k], wa1z, ba1)));
                float pb0 = fmaf(px[k], wb0x, fmaf(py[k], wb0y, fmaf(pz[k], wb0z, bb0)));
                float pb1 = fmaf(px[k], wb1x, fmaf(py[k], wb1y, fmaf(pz[k], wb1z, bb1)));
                acc0 = fmaf(pa0, fe0, acc0);
                acc1 = fmaf(pa1, fe1, acc1);
                float t0 = pb0 * fe0, t1 = pb1 * fe1;
                p10 += t0; p11 += t1;
                p20 = fmaf(t0, t0, p20); p21 = fmaf(t1, t1, p21);
            }
        }
        for (; j < mm; j++) {
            int row = __shfl(rowv, j, 64);
            float px = __shfl(fxv, j, 64);
            float py = __shfl(fyv, j, 64);
            float pz = __shfl(fzv, j, 64);
            u32 l2 = *(const u32*)(lin + (size_t)row * 128 + c);
            float fe0 = fmaf(__uint_as_float(l2 << 16), sc0, sh0);
            float fe1 = fmaf(__uint_as_float(l2 & 0xffff0000u), sc1, sh1);
            float pa0 = fmaf(px, wa0x, fmaf(py, wa0y, fmaf(pz, wa0z, ba0)));
            float pa1 = fmaf(px, wa1x, fmaf(py, wa1y, fmaf(pz, wa1z, ba1)));
            float pb0 = fmaf(px, wb0x, fmaf(py, wb0y, fmaf(pz, wb0z, bb0)));
            float pb1 = fmaf(px, wb1x, fmaf(py, wb1y, fmaf(pz, wb1z, bb1)));
            acc0 = fmaf(pa0, fe0, acc0);
            acc1 = fmaf(pa1, fe1, acc1);
            float t0 = pb0 * fe0, t1 = pb1 * fe1;
            p10 += t0; p11 += t1;
            p20 = fmaf(t0, t0, p20); p21 = fmaf(t1, t1, p21);
        }
        for (int jj = 64; jj < m; jj++) {   // vanishingly rare
            int row = order[beg + jj];
            float px = floorf(xyz[row * 3]);
            float py = floorf(xyz[row * 3 + 1]);
            float pz = floorf(xyz[row * 3 + 2]);
            u32 l2 = *(const u32*)(lin + (size_t)row * 128 + c);
            float fe0 = fmaf(__uint_as_float(l2 << 16), sc0, sh0);
            float fe1 = fmaf(__uint_as_float(l2 & 0xffff0000u), sc1, sh1);
            float pa0 = fmaf(px, wa0x, fmaf(py, wa0y, fmaf(pz, wa0z, ba0)));
            float pa1 = fmaf(px, wa1x, fmaf(py, wa1y, fmaf(pz, wa1z, ba1)));
            float pb0 = fmaf(px, wb0x, fmaf(py, wb0y, fmaf(pz, wb0z, bb0)));
            float pb1 = fmaf(px, wb1x, fmaf(py, wb1y, fmaf(pz, wb1z, bb1)));
            acc0 = fmaf(pa0, fe0, acc0);
            acc1 = fmaf(pa1, fe1, acc1);
            float t0 = pb0 * fe0, t1 = pb1 * fe1;
            p10 += t0; p11 += t1;
            p20 = fmaf(t0, t0, p20); p21 = fmaf(t1, t1, p21);
        }
        float2 st; st.x = acc0; st.y = acc1;
        *(float2*)(feat_add + (size_t)s * 128 + c) = st;
        float fm = (float)m;
        rs0 += p10 - fm * acc0;
        rs1 += p11 - fm * acc1;
        rq0 += fmaf(fm * acc0, acc0, p20 - 2.f * acc0 * p10);
        rq1 += fmaf(fm * acc1, acc1, p21 - 2.f * acc1 * p11);
    }
    atomicAdd(&sSum[c], rs0); atomicAdd(&sSum[c + 1], rs1);
    atomicAdd(&sSq[c], rq0);  atomicAdd(&sSq[c + 1], rq1);
    __syncthreads();
    if (t < 128) {
        int rep = (blockIdx.x & (REP - 1)) * 128;
        atomicAdd(&sum2rep[rep + t], sSum[t]);
        atomicAdd(&sumsq2rep[rep + t], sSq[t]);
    }
    __syncthreads();   // drains all waves' atomics
    if (t == 0) {
        __threadfence();
        sLast = (atomicAdd(done2, 1) == (int)gridDim.x - 1);
    }
    __syncthreads();
    if (sLast && t < 128) {      // fused BN2 finalize (last block only)
        float s = 0.f, qq = 0.f;
#pragma unroll
        for (int rr = 0; rr < REP; rr++) {
            s  += agent_ld(&sum2rep[rr * 128 + t]);
            qq += agent_ld(&sumsq2rep[rr * 128 + t]);
        }
        float mean = s * inv_n;
        float var = qq * inv_n - mean * mean;
        float sc = g2[t] * rsqrtf(var + BN_EPS);
        scale2[t] = sc;
        shift2[t] = be2[t] - mean * sc;
    }
}

// ---------------- K4: final out = relu(bn2(out_pre)) ---- (16 thr/row form) -----
__global__ __launch_bounds__(256) void k_final(
    const u16* __restrict__ lin, const float* __restrict__ xyz, const int* __restrict__ unq,
    const float* __restrict__ scale1, const float* __restrict__ shift1,
    const float* __restrict__ Wp2, const float* __restrict__ bp2,
    const float* __restrict__ feat_add,
    const float* __restrict__ scale2, const float* __restrict__ shift2,
    float* __restrict__ out, int n)
{
    __shared__ float sS[128], sH[128], sW3[384], sB[128], sS2[128], sH2[128];
    int t = threadIdx.x;
    if (t < 128) {
        sS[t] = scale1[t]; sH[t] = shift1[t]; sB[t] = bp2[t];
        sW3[t] = Wp2[t]; sW3[128 + t] = Wp2[128 + t]; sW3[256 + t] = Wp2[256 + t];
        sS2[t] = scale2[t]; sH2[t] = shift2[t];
    }
    __syncthreads();
    int row = blockIdx.x * 16 + (t >> 4);
    if (row >= n) return;
    int c0 = (t & 15) * 8;
    uint4 l8 = *(const uint4*)(lin + (size_t)row * 128 + c0);
    float f[8];
    unpack8(l8, f);
    float px = floorf(xyz[row * 3 + 0]);
    float py = floorf(xyz[row * 3 + 1]);
    float pz = floorf(xyz[row * 3 + 2]);
    int g = unq[row];
    const float4* fa = (const float4*)(feat_add + (size_t)g * 128 + c0);
    float4 fa0 = fa[0], fa1 = fa[1];
    float fav[8] = {fa0.x, fa0.y, fa0.z, fa0.w, fa1.x, fa1.y, fa1.z, fa1.w};
    float o[8];
#pragma unroll
    for (int j = 0; j < 8; j++) {
        int c = c0 + j;
        float fe = fmaf(f[j], sS[c], sH[c]);
        float pw = fmaf(px, sW3[c], fmaf(py, sW3[128 + c], fmaf(pz, sW3[256 + c], sB[c])));
        float v = pw * fe - fav[j];
        v = fmaf(v, sS2[c], sH2[c]);
        o[j] = v > 0.f ? v : 0.f;
    }
    float4 s0, s1;
    s0.x = o[0]; s0.y = o[1]; s0.z = o[2]; s0.w = o[3];
    s1.x = o[4]; s1.y = o[5]; s1.z = o[6]; s1.w = o[7];
    float* op = out + (size_t)row * 128 + c0;
    *(float4*)op = s0;
    *(float4*)(op + 4) = s1;
}

extern "C" void kernel_launch(void* const* d_in, const int* in_sizes, int n_in,
                              void* d_out, int out_size, void* d_ws, size_t ws_size,
                              hipStream_t stream)
{
    const float* xyz      = (const float*)d_in[0];
    const float* feat_all = (const float*)d_in[1];
    const int*   unq      = (const int*)d_in[2];
    const float* W_pre    = (const float*)d_in[3];
    const float* b_pre    = (const float*)d_in[4];
    const float* g1       = (const float*)d_in[5];
    const float* be1      = (const float*)d_in[6];
    const float* Wp1      = (const float*)d_in[7];
    const float* bp1      = (const float*)d_in[8];
    const float* Wp2      = (const float*)d_in[9];
    const float* bp2      = (const float*)d_in[10];
    const float* g2       = (const float*)d_in[11];
    const float* be2      = (const float*)d_in[12];
    (void)n_in; (void)out_size; (void)ws_size;

    const int n = in_sizes[0] / 3;   // 400000

    char* ws = (char*)d_ws;
    // ---- workspace layout (aliases noted) ----
    float* sum1rep   = (float*)(ws + 0);        // [REP][128] = 16384 B
    float* sumsq1rep = (float*)(ws + 16384);    // 16384 B
    float* sum2rep   = (float*)(ws + 32768);    // 16384 B
    float* sumsq2rep = (float*)(ws + 49152);    // 16384 B
    float* scale1    = (float*)(ws + 65536);
    float* shift1    = (float*)(ws + 66048);
    float* scale2    = (float*)(ws + 66560);
    float* shift2    = (float*)(ws + 67072);    // ends 67584
    int*   done1     = (int*)(ws + 67584);
    int*   done2     = (int*)(ws + 67588);      // zero region = [0, 67600)
    int*   offs      = (int*)(ws + 67648);      // 30001 ints, ends 187652
    int*   cursor    = (int*)(ws + 187712);     // 30000 ints, ends 307712
    u16*   wt_f      = (u16*)(ws + 187712);     // 32768 B, ALIASES cursor (dead until k_scan)
    int*   order     = (int*)(ws + 307712);     // 400000 ints, ends 1907712
    int*   cnt       = (int*)(ws + 307712);     // 30000 ints, ALIASES order (dead after k_scan)
    float* feat_add  = (float*)(ws + 1907712);  // 15360000 B, ends 17267712
    u16*   lin       = (u16*)(ws + 17267712);   // 102400000 B, ends 119667712

    const float inv_n = 1.0f / n;

    k_prep<<<8, 512, 0, stream>>>(W_pre, wt_f, (u32*)ws, cnt);
    k_gemm_bn1<<<(n + 511) / 512, 512, 0, stream>>>(feat_all, wt_f, b_pre, unq, cnt,
                                                    lin, sum1rep, sumsq1rep,
                                                    g1, be1, scale1, shift1, done1, inv_n, n);
    k_scan<<<1, 1024, 0, stream>>>(cnt, offs, cursor);
    k_scatter_idx<<<(n + 255) / 256, 256, 0, stream>>>(unq, cursor, order, n);
    k_segsum<<<1876, 256, 0, stream>>>(lin, xyz, order, offs, scale1, shift1,
                                       Wp1, bp1, Wp2, bp2, feat_add, sum2rep, sumsq2rep,
                                       g2, be2, scale2, shift2, done2, inv_n, GSEG);
    k_final<<<(n + 15) / 16, 256, 0, stream>>>(lin, xyz, unq, scale1, shift1, Wp2, bp2,
                                               feat_add, scale2, shift2, (float*)d_out, n);
}

// Round 8
// 523.190 us; speedup vs baseline: 1.1492x; 1.1492x over previous
//
#include <hip/hip_runtime.h>
#include <hip/hip_bf16.h>

typedef unsigned int u32;
typedef unsigned short u16;
typedef __attribute__((ext_vector_type(8))) short short8;
typedef __attribute__((ext_vector_type(4))) float floatx4;

#define COUT 128
#define GSEG 30000
#define BN_EPS 1e-3f
#define REP 32            // stat-accumulator replicas (kills same-address atomic serialization)

__device__ __forceinline__ u32 f2bf(float x) {
    u32 u = __float_as_uint(x);
    return (u + 0x7fffu + ((u >> 16) & 1u)) >> 16;   // RNE bf16
}
__device__ __forceinline__ float bf2f(u32 b) { return __uint_as_float(b << 16); }

__device__ __forceinline__ void unpack8(uint4 v, float* f) {
    f[0] = __uint_as_float(v.x << 16); f[1] = __uint_as_float(v.x & 0xffff0000u);
    f[2] = __uint_as_float(v.y << 16); f[3] = __uint_as_float(v.y & 0xffff0000u);
    f[4] = __uint_as_float(v.z << 16); f[5] = __uint_as_float(v.z & 0xffff0000u);
    f[6] = __uint_as_float(v.w << 16); f[7] = __uint_as_float(v.w & 0xffff0000u);
}

// ---------------- prep: W -> bf16 hi/lo in MFMA FRAGMENT ORDER ----------------
__global__ __launch_bounds__(512) void k_prep_w(
    const float* __restrict__ W, u16* __restrict__ wt_f)
{
    int t = threadIdx.x;
    for (int f = t; f < 8192; f += 512) {
        int ch = f >> 3, e = f & 7;
        int ct = ch >> 7, ks = (ch >> 6) & 1, lane = ch & 63;
        int c = ct * 16 + (lane & 15);
        int k = ks * 32 + (lane >> 4) * 8 + e;
        float w = W[k * 128 + c];
        u32 hb = f2bf(w);
        float lo = w - bf2f(hb);
        wt_f[f] = (u16)hb;
        wt_f[8192 + f] = (u16)f2bf(lo);
    }
}

// ---------------- K1: lin = A @ W + b (split-bf16 MFMA) + BN1 stats + hist ----
// 512 thr (8 waves), 512 ROWS/block in 4 pipelined iterations. W staged once.
// __launch_bounds__(512, 2): min 2 waves/EU -> VGPR budget 128 so the av[2][4]
// double-buffer is actually register-resident (VGPR=56 before proved the
// compiler was sinking the prefetch -> serial HBM latency every iteration).
__global__ __launch_bounds__(512, 2) void k_gemm_bn1(
    const float* __restrict__ A, const u16* __restrict__ wt_f,
    const float* __restrict__ bias, const int* __restrict__ unq, int* __restrict__ cnt,
    u16* __restrict__ lin, float* __restrict__ sum1rep, float* __restrict__ sumsq1rep, int n)
{
    __shared__ u16 smw[16384];   // fragment-order W: hi [0,8192), lo [8192,16384)
    __shared__ float sSum[128], sSq[128];

    const int t = threadIdx.x;
    const int base = blockIdx.x * 512;
    if (t < 128) { sSum[t] = 0.f; sSq[t] = 0.f; }

    // fused histogram: one row per thread (512 rows/block)
    if (base + t < n) atomicAdd(&cnt[unq[base + t]], 1);

    const int lane = t & 63, wv = t >> 6;
    const int r = lane & 15, q = lane >> 4;
    const int rw0 = wv * 16;

    // stage W to LDS: 2048 coalesced 16B chunks (conflict-free)
#pragma unroll
    for (int j = 0; j < 4; j++) {
        int chunk = j * 512 + t;
        *(uint4*)&smw[chunk * 8] = *(const uint4*)(wt_f + chunk * 8);
    }

    // prime iter-0 A fragments
    float4 av[2][4];
    {
        int row_a = base + rw0 + r;
        const float* ap = A + (size_t)row_a * 64;
        bool ok = row_a < n;
#pragma unroll
        for (int ks = 0; ks < 2; ks++) {
            av[0][ks * 2]     = ok ? *(const float4*)(ap + ks * 32 + q * 8)     : make_float4(0.f, 0.f, 0.f, 0.f);
            av[0][ks * 2 + 1] = ok ? *(const float4*)(ap + ks * 32 + q * 8 + 4) : make_float4(0.f, 0.f, 0.f, 0.f);
        }
    }
    __syncthreads();   // W staged; sSum/sSq init visible

    // bias per ct (hoisted; L1-resident)
    float bv[8];
#pragma unroll
    for (int ct = 0; ct < 8; ct++) bv[ct] = bias[ct * 16 + r];

    float ssum[8], ssq[8];
#pragma unroll
    for (int ct = 0; ct < 8; ct++) { ssum[ct] = 0.f; ssq[ct] = 0.f; }

    const int fbase = lane * 8;

#pragma unroll
    for (int it = 0; it < 4; it++) {
        const int cur = it & 1, nxt = cur ^ 1;
        // prefetch next iter's A (overlaps MFMA below)
        if (it < 3) {
            int row_n = base + (it + 1) * 128 + rw0 + r;
            const float* ap = A + (size_t)row_n * 64;
            bool ok = row_n < n;
#pragma unroll
            for (int ks = 0; ks < 2; ks++) {
                av[nxt][ks * 2]     = ok ? *(const float4*)(ap + ks * 32 + q * 8)     : make_float4(0.f, 0.f, 0.f, 0.f);
                av[nxt][ks * 2 + 1] = ok ? *(const float4*)(ap + ks * 32 + q * 8 + 4) : make_float4(0.f, 0.f, 0.f, 0.f);
            }
        }
        // convert current A fp32 -> bf16 hi/lo
        short8 arh[2], arl[2];
#pragma unroll
        for (int ks = 0; ks < 2; ks++) {
            float vv[8] = {av[cur][ks * 2].x, av[cur][ks * 2].y, av[cur][ks * 2].z, av[cur][ks * 2].w,
                           av[cur][ks * 2 + 1].x, av[cur][ks * 2 + 1].y, av[cur][ks * 2 + 1].z, av[cur][ks * 2 + 1].w};
#pragma unroll
            for (int i = 0; i < 8; i++) {
                u32 hb = f2bf(vv[i]);
                float lo = vv[i] - bf2f(hb);
                arh[ks][i] = (short)(u16)hb;
                arl[ks][i] = (short)(u16)f2bf(lo);
            }
        }

        floatx4 acc[8];
#pragma unroll
        for (int ct = 0; ct < 8; ct++) acc[ct] = (floatx4){0.f, 0.f, 0.f, 0.f};

#pragma unroll
        for (int ct = 0; ct < 8; ct++) {
#pragma unroll
            for (int ks = 0; ks < 2; ks++) {
                int fo = (ct * 2 + ks) * 512 + fbase;
                short8 wh = *(const short8*)&smw[fo];
                short8 wl = *(const short8*)&smw[8192 + fo];
                acc[ct] = __builtin_amdgcn_mfma_f32_16x16x32_bf16(arh[ks], wh, acc[ct], 0, 0, 0);
                acc[ct] = __builtin_amdgcn_mfma_f32_16x16x32_bf16(arl[ks], wh, acc[ct], 0, 0, 0);
                acc[ct] = __builtin_amdgcn_mfma_f32_16x16x32_bf16(arh[ks], wl, acc[ct], 0, 0, 0);
            }
        }

        // epilogue: bias + stats (register-resident) + direct u16 stores of lin
#pragma unroll
        for (int ct = 0; ct < 8; ct++) {
            int c = ct * 16 + r;
#pragma unroll
            for (int i = 0; i < 4; i++) {
                int grow = base + it * 128 + rw0 + q * 4 + i;
                float v = acc[ct][i] + bv[ct];
                if (grow < n) {
                    ssum[ct] += v; ssq[ct] += v * v;
                    lin[(size_t)grow * 128 + c] = (u16)f2bf(v);
                }
            }
        }
    }

    // stats: wave reduce (over q-groups) -> LDS -> one replicated global atomic round
#pragma unroll
    for (int ct = 0; ct < 8; ct++) {
        float s = ssum[ct], qq = ssq[ct];
        s += __shfl_xor(s, 16, 64); qq += __shfl_xor(qq, 16, 64);
        s += __shfl_xor(s, 32, 64); qq += __shfl_xor(qq, 32, 64);
        if (lane < 16) { atomicAdd(&sSum[ct * 16 + r], s); atomicAdd(&sSq[ct * 16 + r], qq); }
    }
    __syncthreads();
    if (t < 128) {
        int rep = (blockIdx.x & (REP - 1)) * 128;
        atomicAdd(&sum1rep[rep + t], sSum[t]);
        atomicAdd(&sumsq1rep[rep + t], sSq[t]);
    }
}

// ---------------- finalize BN params (reduces REP replicas) ----------------
__global__ void k_fin(const float* __restrict__ sumrep, const float* __restrict__ sqrep,
                      const float* __restrict__ g, const float* __restrict__ be,
                      float* __restrict__ scale, float* __restrict__ shift, float inv_n)
{
    int c = threadIdx.x;
    float s = 0.f, q = 0.f;
#pragma unroll
    for (int r = 0; r < REP; r++) { s += sumrep[r * 128 + c]; q += sqrep[r * 128 + c]; }
    float mean = s * inv_n;
    float var = q * inv_n - mean * mean;
    float sc = g[c] * rsqrtf(var + BN_EPS);
    scale[c] = sc;
    shift[c] = be[c] - mean * sc;
}

// ---------------- K2b: single-pass exclusive scan (1024 thr x 32 elems) -------
__global__ __launch_bounds__(1024) void k_scan(const int* __restrict__ cnt,
                                               int* __restrict__ offs,
                                               int* __restrict__ cursor)
{
    __shared__ int wsum[16];
    int t = threadIdx.x, lane = t & 63, wv = t >> 6;
    int base = t * 32;
    int v[32];
    int s = 0;
    if (base + 32 <= GSEG) {
        const int4* cp = (const int4*)(cnt + base);
#pragma unroll
        for (int j = 0; j < 8; j++) {
            int4 q = cp[j];
            v[j * 4 + 0] = q.x; v[j * 4 + 1] = q.y; v[j * 4 + 2] = q.z; v[j * 4 + 3] = q.w;
            s += q.x + q.y + q.z + q.w;
        }
    } else {
#pragma unroll
        for (int j = 0; j < 32; j++) {
            int idx = base + j;
            int x = (idx < GSEG) ? cnt[idx] : 0;
            v[j] = x; s += x;
        }
    }
    int x = s;
#pragma unroll
    for (int d = 1; d < 64; d <<= 1) {
        int u = __shfl_up(x, d, 64);
        if (lane >= d) x += u;
    }
    if (lane == 63) wsum[wv] = x;
    __syncthreads();
    if (t < 16) {
        int w = wsum[t];
#pragma unroll
        for (int d = 1; d < 16; d <<= 1) {
            int u = __shfl_up(w, d, 16);
            if (t >= d) w += u;
        }
        wsum[t] = w;
    }
    __syncthreads();
    int run = (wv ? wsum[wv - 1] : 0) + (x - s);
#pragma unroll
    for (int j = 0; j < 32; j++) {
        int idx = base + j;
        if (idx < GSEG) { offs[idx] = run; cursor[idx] = run; }
        run += v[j];
    }
    if (t == 1023) offs[GSEG] = wsum[15];
}

// ---------------- K2c: scatter row indices into segment-sorted order -----------
__global__ __launch_bounds__(256) void k_scatter_idx(const int* __restrict__ unq,
                                                     int* __restrict__ cursor,
                                                     int* __restrict__ order, int n)
{
    int i = blockIdx.x * 256 + threadIdx.x;
    if (i < n) {
        int pos = atomicAdd(&cursor[unq[i]], 1);
        order[pos] = i;
    }
}

// ---------------- K2d: per-segment gather sum + fused BN2 raw moments ----------
// feat_add[s][c] = acc = sum pw1*fe ; BN2 stats via P1 = sum pw2*fe, P2 = sum (pw2*fe)^2:
//   sum out = P1 - m*acc ; sum out^2 = P2 - 2*acc*P1 + m*acc^2
__global__ __launch_bounds__(256) void k_segsum(
    const u16* __restrict__ lin, const float* __restrict__ xyz,
    const int* __restrict__ order, const int* __restrict__ offs,
    const float* __restrict__ scale1, const float* __restrict__ shift1,
    const float* __restrict__ Wp1, const float* __restrict__ bp1,
    const float* __restrict__ Wp2, const float* __restrict__ bp2,
    float* __restrict__ feat_add, float* __restrict__ sum2rep, float* __restrict__ sumsq2rep,
    int nseg)
{
    __shared__ float sSum[128], sSq[128];
    const int t = threadIdx.x;
    if (t < 128) { sSum[t] = 0.f; sSq[t] = 0.f; }
    __syncthreads();
    const int wave = t >> 6, lane = t & 63;
    const int c = lane * 2;
    const float wa0x = Wp1[c],     wa0y = Wp1[128 + c],     wa0z = Wp1[256 + c],     ba0 = bp1[c];
    const float wa1x = Wp1[c + 1], wa1y = Wp1[128 + c + 1], wa1z = Wp1[256 + c + 1], ba1 = bp1[c + 1];
    const float wb0x = Wp2[c],     wb0y = Wp2[128 + c],     wb0z = Wp2[256 + c],     bb0 = bp2[c];
    const float wb1x = Wp2[c + 1], wb1y = Wp2[128 + c + 1], wb1z = Wp2[256 + c + 1], bb1 = bp2[c + 1];
    const float sc0 = scale1[c], sh0 = shift1[c];
    const float sc1 = scale1[c + 1], sh1 = shift1[c + 1];
    float rs0 = 0.f, rs1 = 0.f, rq0 = 0.f, rq1 = 0.f;
    const int stride = gridDim.x * 4;
    for (int s = blockIdx.x * 4 + wave; s < nseg; s += stride) {
        const int beg = offs[s], end = offs[s + 1];
        const int m = end - beg;
        // prefetch rows + pre-floored xyz into per-lane registers (one per row)
        int rowv = 0; float fxv = 0.f, fyv = 0.f, fzv = 0.f;
        if (lane < m) {
            rowv = order[beg + lane];
            float2 xy = *(const float2*)(xyz + rowv * 3);
            fxv = floorf(xy.x);
            fyv = floorf(xy.y);
            fzv = floorf(xyz[rowv * 3 + 2]);
        }
        float acc0 = 0.f, acc1 = 0.f, p10 = 0.f, p11 = 0.f, p20 = 0.f, p21 = 0.f;
        const int mm = m < 64 ? m : 64;
        int j = 0;
        // 4-row unroll: four independent 256B gathers in flight
        for (; j + 4 <= mm; j += 4) {
            int   rw[4]; float px[4], py[4], pz[4]; u32 ll[4];
#pragma unroll
            for (int k = 0; k < 4; k++) {
                rw[k] = __shfl(rowv, j + k, 64);
                px[k] = __shfl(fxv, j + k, 64);
                py[k] = __shfl(fyv, j + k, 64);
                pz[k] = __shfl(fzv, j + k, 64);
            }
#pragma unroll
            for (int k = 0; k < 4; k++)
                ll[k] = *(const u32*)(lin + (size_t)rw[k] * 128 + c);
#pragma unroll
            for (int k = 0; k < 4; k++) {
                float fe0 = fmaf(__uint_as_float(ll[k] << 16), sc0, sh0);
                float fe1 = fmaf(__uint_as_float(ll[k] & 0xffff0000u), sc1, sh1);
                float pa0 = fmaf(px[k], wa0x, fmaf(py[k], wa0y, fmaf(pz[k], wa0z, ba0)));
                float pa1 = fmaf(px[k], wa1x, fmaf(py[k], wa1y, fmaf(pz[k], wa1z, ba1)));
                float pb0 = fmaf(px[k], wb0x, fmaf(py[k], wb0y, fmaf(pz[k], wb0z, bb0)));
                float pb1 = fmaf(px[k], wb1x, fmaf(py[k], wb1y, fmaf(pz[k], wb1z, bb1)));
                acc0 = fmaf(pa0, fe0, acc0);
                acc1 = fmaf(pa1, fe1, acc1);
                float t0 = pb0 * fe0, t1 = pb1 * fe1;
                p10 += t0; p11 += t1;
                p20 = fmaf(t0, t0, p20); p21 = fmaf(t1, t1, p21);
            }
        }
        for (; j < mm; j++) {
            int row = __shfl(rowv, j, 64);
            float px = __shfl(fxv, j, 64);
            float py = __shfl(fyv, j, 64);
            float pz = __shfl(fzv, j, 64);
            u32 l2 = *(const u32*)(lin + (size_t)row * 128 + c);
            float fe0 = fmaf(__uint_as_float(l2 << 16), sc0, sh0);
            float fe1 = fmaf(__uint_as_float(l2 & 0xffff0000u), sc1, sh1);
            float pa0 = fmaf(px, wa0x, fmaf(py, wa0y, fmaf(pz, wa0z, ba0)));
            float pa1 = fmaf(px, wa1x, fmaf(py, wa1y, fmaf(pz, wa1z, ba1)));
            float pb0 = fmaf(px, wb0x, fmaf(py, wb0y, fmaf(pz, wb0z, bb0)));
            float pb1 = fmaf(px, wb1x, fmaf(py, wb1y, fmaf(pz, wb1z, bb1)));
            acc0 = fmaf(pa0, fe0, acc0);
            acc1 = fmaf(pa1, fe1, acc1);
            float t0 = pb0 * fe0, t1 = pb1 * fe1;
            p10 += t0; p11 += t1;
            p20 = fmaf(t0, t0, p20); p21 = fmaf(t1, t1, p21);
        }
        for (int jj = 64; jj < m; jj++) {   // vanishingly rare
            int row = order[beg + jj];
            float px = floorf(xyz[row * 3]);
            float py = floorf(xyz[row * 3 + 1]);
            float pz = floorf(xyz[row * 3 + 2]);
            u32 l2 = *(const u32*)(lin + (size_t)row * 128 + c);
            float fe0 = fmaf(__uint_as_float(l2 << 16), sc0, sh0);
            float fe1 = fmaf(__uint_as_float(l2 & 0xffff0000u), sc1, sh1);
            float pa0 = fmaf(px, wa0x, fmaf(py, wa0y, fmaf(pz, wa0z, ba0)));
            float pa1 = fmaf(px, wa1x, fmaf(py, wa1y, fmaf(pz, wa1z, ba1)));
            float pb0 = fmaf(px, wb0x, fmaf(py, wb0y, fmaf(pz, wb0z, bb0)));
            float pb1 = fmaf(px, wb1x, fmaf(py, wb1y, fmaf(pz, wb1z, bb1)));
            acc0 = fmaf(pa0, fe0, acc0);
            acc1 = fmaf(pa1, fe1, acc1);
            float t0 = pb0 * fe0, t1 = pb1 * fe1;
            p10 += t0; p11 += t1;
            p20 = fmaf(t0, t0, p20); p21 = fmaf(t1, t1, p21);
        }
        float2 st; st.x = acc0; st.y = acc1;
        *(float2*)(feat_add + (size_t)s * 128 + c) = st;
        float fm = (float)m;
        rs0 += p10 - fm * acc0;
        rs1 += p11 - fm * acc1;
        rq0 += fmaf(fm * acc0, acc0, p20 - 2.f * acc0 * p10);
        rq1 += fmaf(fm * acc1, acc1, p21 - 2.f * acc1 * p11);
    }
    atomicAdd(&sSum[c], rs0); atomicAdd(&sSum[c + 1], rs1);
    atomicAdd(&sSq[c], rq0);  atomicAdd(&sSq[c + 1], rq1);
    __syncthreads();
    if (t < 128) {
        int rep = (blockIdx.x & (REP - 1)) * 128;
        atomicAdd(&sum2rep[rep + t], sSum[t]);
        atomicAdd(&sumsq2rep[rep + t], sSq[t]);
    }
}

// ---------------- K4: final out = relu(bn2(out_pre)) ---- (16 thr/row form) -----
__global__ __launch_bounds__(256) void k_final(
    const u16* __restrict__ lin, const float* __restrict__ xyz, const int* __restrict__ unq,
    const float* __restrict__ scale1, const float* __restrict__ shift1,
    const float* __restrict__ Wp2, const float* __restrict__ bp2,
    const float* __restrict__ feat_add,
    const float* __restrict__ scale2, const float* __restrict__ shift2,
    float* __restrict__ out, int n)
{
    __shared__ float sS[128], sH[128], sW3[384], sB[128], sS2[128], sH2[128];
    int t = threadIdx.x;
    if (t < 128) {
        sS[t] = scale1[t]; sH[t] = shift1[t]; sB[t] = bp2[t];
        sW3[t] = Wp2[t]; sW3[128 + t] = Wp2[128 + t]; sW3[256 + t] = Wp2[256 + t];
        sS2[t] = scale2[t]; sH2[t] = shift2[t];
    }
    __syncthreads();
    int row = blockIdx.x * 16 + (t >> 4);
    if (row >= n) return;
    int c0 = (t & 15) * 8;
    uint4 l8 = *(const uint4*)(lin + (size_t)row * 128 + c0);
    float f[8];
    unpack8(l8, f);
    float px = floorf(xyz[row * 3 + 0]);
    float py = floorf(xyz[row * 3 + 1]);
    float pz = floorf(xyz[row * 3 + 2]);
    int g = unq[row];
    const float4* fa = (const float4*)(feat_add + (size_t)g * 128 + c0);
    float4 fa0 = fa[0], fa1 = fa[1];
    float fav[8] = {fa0.x, fa0.y, fa0.z, fa0.w, fa1.x, fa1.y, fa1.z, fa1.w};
    float o[8];
#pragma unroll
    for (int j = 0; j < 8; j++) {
        int c = c0 + j;
        float fe = fmaf(f[j], sS[c], sH[c]);
        float pw = fmaf(px, sW3[c], fmaf(py, sW3[128 + c], fmaf(pz, sW3[256 + c], sB[c])));
        float v = pw * fe - fav[j];
        v = fmaf(v, sS2[c], sH2[c]);
        o[j] = v > 0.f ? v : 0.f;
    }
    float4 s0, s1;
    s0.x = o[0]; s0.y = o[1]; s0.z = o[2]; s0.w = o[3];
    s1.x = o[4]; s1.y = o[5]; s1.z = o[6]; s1.w = o[7];
    float* op = out + (size_t)row * 128 + c0;
    *(float4*)op = s0;
    *(float4*)(op + 4) = s1;
}

extern "C" void kernel_launch(void* const* d_in, const int* in_sizes, int n_in,
                              void* d_out, int out_size, void* d_ws, size_t ws_size,
                              hipStream_t stream)
{
    const float* xyz      = (const float*)d_in[0];
    const float* feat_all = (const float*)d_in[1];
    const int*   unq      = (const int*)d_in[2];
    const float* W_pre    = (const float*)d_in[3];
    const float* b_pre    = (const float*)d_in[4];
    const float* g1       = (const float*)d_in[5];
    const float* be1      = (const float*)d_in[6];
    const float* Wp1      = (const float*)d_in[7];
    const float* bp1      = (const float*)d_in[8];
    const float* Wp2      = (const float*)d_in[9];
    const float* bp2      = (const float*)d_in[10];
    const float* g2       = (const float*)d_in[11];
    const float* be2      = (const float*)d_in[12];
    (void)n_in; (void)out_size; (void)ws_size;

    const int n = in_sizes[0] / 3;   // 400000

    char* ws = (char*)d_ws;
    // ---- workspace layout (aliases noted) ----
    float* sum1rep   = (float*)(ws + 0);        // [REP][128] = 16384 B
    float* sumsq1rep = (float*)(ws + 16384);    // 16384 B
    float* sum2rep   = (float*)(ws + 32768);    // 16384 B
    float* sumsq2rep = (float*)(ws + 49152);    // 16384 B
    float* scale1    = (float*)(ws + 65536);
    float* shift1    = (float*)(ws + 66048);
    float* scale2    = (float*)(ws + 66560);
    float* shift2    = (float*)(ws + 67072);    // ends 67584
    int*   offs      = (int*)(ws + 67584);      // 30001 ints, ends 187588
    int*   cursor    = (int*)(ws + 187648);     // 30000 ints, ends 307648
    u16*   wt_f      = (u16*)(ws + 187648);     // 32768 B, ALIASES cursor (dead until k_scan)
    int*   order     = (int*)(ws + 307648);     // 400000 ints, ends 1907648
    int*   cnt       = (int*)(ws + 307648);     // 30000 ints, ALIASES order (dead after k_scan)
    float* feat_add  = (float*)(ws + 1907648);  // 30000*128 f = 15360000 B, ends 17267648
    u16*   lin       = (u16*)(ws + 17267648);   // 400000*128 bf16 = 102400000 B, ends 119667648

    hipMemsetAsync(ws, 0, 65536, stream);                 // replica stats
    hipMemsetAsync(ws + 307648, 0, 120000, stream);       // cnt

    k_prep_w<<<1, 512, 0, stream>>>(W_pre, wt_f);
    k_gemm_bn1<<<(n + 511) / 512, 512, 0, stream>>>(feat_all, wt_f, b_pre, unq, cnt,
                                                    lin, sum1rep, sumsq1rep, n);
    k_fin<<<1, 128, 0, stream>>>(sum1rep, sumsq1rep, g1, be1, scale1, shift1, 1.0f / n);

    k_scan<<<1, 1024, 0, stream>>>(cnt, offs, cursor);
    k_scatter_idx<<<(n + 255) / 256, 256, 0, stream>>>(unq, cursor, order, n);
    k_segsum<<<1876, 256, 0, stream>>>(lin, xyz, order, offs, scale1, shift1,
                                       Wp1, bp1, Wp2, bp2, feat_add, sum2rep, sumsq2rep, GSEG);
    k_fin<<<1, 128, 0, stream>>>(sum2rep, sumsq2rep, g2, be2, scale2, shift2, 1.0f / n);
    k_final<<<(n + 15) / 16, 256, 0, stream>>>(lin, xyz, unq, scale1, shift1, Wp2, bp2,
                                               feat_add, scale2, shift2, (float*)d_out, n);
}

// Round 9
// 508.233 us; speedup vs baseline: 1.1830x; 1.0294x over previous
//
#include <hip/hip_runtime.h>
#include <hip/hip_bf16.h>

typedef unsigned int u32;
typedef unsigned short u16;
typedef __attribute__((ext_vector_type(8))) short short8;
typedef __attribute__((ext_vector_type(4))) float floatx4;

#define COUT 128
#define GSEG 30000
#define BN_EPS 1e-3f
#define REP 32            // stat-accumulator replicas (kills same-address atomic serialization)

__device__ __forceinline__ u32 f2bf(float x) {
    u32 u = __float_as_uint(x);
    return (u + 0x7fffu + ((u >> 16) & 1u)) >> 16;   // RNE bf16
}
__device__ __forceinline__ float bf2f(u32 b) { return __uint_as_float(b << 16); }

__device__ __forceinline__ void unpack8(uint4 v, float* f) {
    f[0] = __uint_as_float(v.x << 16); f[1] = __uint_as_float(v.x & 0xffff0000u);
    f[2] = __uint_as_float(v.y << 16); f[3] = __uint_as_float(v.y & 0xffff0000u);
    f[4] = __uint_as_float(v.z << 16); f[5] = __uint_as_float(v.z & 0xffff0000u);
    f[6] = __uint_as_float(v.w << 16); f[7] = __uint_as_float(v.w & 0xffff0000u);
}

// ---------------- prep: W -> bf16 hi/lo in MFMA FRAGMENT ORDER ----------------
__global__ __launch_bounds__(512) void k_prep_w(
    const float* __restrict__ W, u16* __restrict__ wt_f)
{
    int t = threadIdx.x;
    for (int f = t; f < 8192; f += 512) {
        int ch = f >> 3, e = f & 7;
        int ct = ch >> 7, ks = (ch >> 6) & 1, lane = ch & 63;
        int c = ct * 16 + (lane & 15);
        int k = ks * 32 + (lane >> 4) * 8 + e;
        float w = W[k * 128 + c];
        u32 hb = f2bf(w);
        float lo = w - bf2f(hb);
        wt_f[f] = (u16)hb;
        wt_f[8192 + f] = (u16)f2bf(lo);
    }
}

// ---------------- K1: lin = A @ W + b (split-bf16 MFMA) + BN1 stats + hist ----
// 512 thr (8 waves), 512 ROWS/block in 4 pipelined iterations. W staged once.
__global__ __launch_bounds__(512) void k_gemm_bn1(
    const float* __restrict__ A, const u16* __restrict__ wt_f,
    const float* __restrict__ bias, const int* __restrict__ unq, int* __restrict__ cnt,
    u16* __restrict__ lin, float* __restrict__ sum1rep, float* __restrict__ sumsq1rep, int n)
{
    __shared__ u16 smw[16384];   // fragment-order W: hi [0,8192), lo [8192,16384)
    __shared__ float sSum[128], sSq[128];

    const int t = threadIdx.x;
    const int base = blockIdx.x * 512;
    if (t < 128) { sSum[t] = 0.f; sSq[t] = 0.f; }

    // fused histogram: one row per thread (512 rows/block)
    if (base + t < n) atomicAdd(&cnt[unq[base + t]], 1);

    const int lane = t & 63, wv = t >> 6;
    const int r = lane & 15, q = lane >> 4;
    const int rw0 = wv * 16;

    // stage W to LDS: 2048 coalesced 16B chunks (conflict-free)
#pragma unroll
    for (int j = 0; j < 4; j++) {
        int chunk = j * 512 + t;
        *(uint4*)&smw[chunk * 8] = *(const uint4*)(wt_f + chunk * 8);
    }

    // prime iter-0 A fragments
    float4 av[2][4];
    {
        int row_a = base + rw0 + r;
        const float* ap = A + (size_t)row_a * 64;
        bool ok = row_a < n;
#pragma unroll
        for (int ks = 0; ks < 2; ks++) {
            av[0][ks * 2]     = ok ? *(const float4*)(ap + ks * 32 + q * 8)     : make_float4(0.f, 0.f, 0.f, 0.f);
            av[0][ks * 2 + 1] = ok ? *(const float4*)(ap + ks * 32 + q * 8 + 4) : make_float4(0.f, 0.f, 0.f, 0.f);
        }
    }
    __syncthreads();   // W staged; sSum/sSq init visible

    // bias per ct (hoisted; L1-resident)
    float bv[8];
#pragma unroll
    for (int ct = 0; ct < 8; ct++) bv[ct] = bias[ct * 16 + r];

    float ssum[8], ssq[8];
#pragma unroll
    for (int ct = 0; ct < 8; ct++) { ssum[ct] = 0.f; ssq[ct] = 0.f; }

    const int fbase = lane * 8;

#pragma unroll
    for (int it = 0; it < 4; it++) {
        const int cur = it & 1, nxt = cur ^ 1;
        // prefetch next iter's A (overlaps MFMA below)
        if (it < 3) {
            int row_n = base + (it + 1) * 128 + rw0 + r;
            const float* ap = A + (size_t)row_n * 64;
            bool ok = row_n < n;
#pragma unroll
            for (int ks = 0; ks < 2; ks++) {
                av[nxt][ks * 2]     = ok ? *(const float4*)(ap + ks * 32 + q * 8)     : make_float4(0.f, 0.f, 0.f, 0.f);
                av[nxt][ks * 2 + 1] = ok ? *(const float4*)(ap + ks * 32 + q * 8 + 4) : make_float4(0.f, 0.f, 0.f, 0.f);
            }
        }
        // convert current A fp32 -> bf16 hi/lo
        short8 arh[2], arl[2];
#pragma unroll
        for (int ks = 0; ks < 2; ks++) {
            float vv[8] = {av[cur][ks * 2].x, av[cur][ks * 2].y, av[cur][ks * 2].z, av[cur][ks * 2].w,
                           av[cur][ks * 2 + 1].x, av[cur][ks * 2 + 1].y, av[cur][ks * 2 + 1].z, av[cur][ks * 2 + 1].w};
#pragma unroll
            for (int i = 0; i < 8; i++) {
                u32 hb = f2bf(vv[i]);
                float lo = vv[i] - bf2f(hb);
                arh[ks][i] = (short)(u16)hb;
                arl[ks][i] = (short)(u16)f2bf(lo);
            }
        }

        floatx4 acc[8];
#pragma unroll
        for (int ct = 0; ct < 8; ct++) acc[ct] = (floatx4){0.f, 0.f, 0.f, 0.f};

#pragma unroll
        for (int ct = 0; ct < 8; ct++) {
#pragma unroll
            for (int ks = 0; ks < 2; ks++) {
                int fo = (ct * 2 + ks) * 512 + fbase;
                short8 wh = *(const short8*)&smw[fo];
                short8 wl = *(const short8*)&smw[8192 + fo];
                acc[ct] = __builtin_amdgcn_mfma_f32_16x16x32_bf16(arh[ks], wh, acc[ct], 0, 0, 0);
                acc[ct] = __builtin_amdgcn_mfma_f32_16x16x32_bf16(arl[ks], wh, acc[ct], 0, 0, 0);
                acc[ct] = __builtin_amdgcn_mfma_f32_16x16x32_bf16(arh[ks], wl, acc[ct], 0, 0, 0);
            }
        }

        // epilogue: bias + stats (register-resident) + direct u16 stores of lin
#pragma unroll
        for (int ct = 0; ct < 8; ct++) {
            int c = ct * 16 + r;
#pragma unroll
            for (int i = 0; i < 4; i++) {
                int grow = base + it * 128 + rw0 + q * 4 + i;
                float v = acc[ct][i] + bv[ct];
                if (grow < n) {
                    ssum[ct] += v; ssq[ct] += v * v;
                    lin[(size_t)grow * 128 + c] = (u16)f2bf(v);
                }
            }
        }
    }

    // stats: wave reduce (over q-groups) -> LDS -> one replicated global atomic round
#pragma unroll
    for (int ct = 0; ct < 8; ct++) {
        float s = ssum[ct], qq = ssq[ct];
        s += __shfl_xor(s, 16, 64); qq += __shfl_xor(qq, 16, 64);
        s += __shfl_xor(s, 32, 64); qq += __shfl_xor(qq, 32, 64);
        if (lane < 16) { atomicAdd(&sSum[ct * 16 + r], s); atomicAdd(&sSq[ct * 16 + r], qq); }
    }
    __syncthreads();
    if (t < 128) {
        int rep = (blockIdx.x & (REP - 1)) * 128;
        atomicAdd(&sum1rep[rep + t], sSum[t]);
        atomicAdd(&sumsq1rep[rep + t], sSq[t]);
    }
}

// ---------------- finalize BN params (reduces REP replicas) ----------------
__global__ void k_fin(const float* __restrict__ sumrep, const float* __restrict__ sqrep,
                      const float* __restrict__ g, const float* __restrict__ be,
                      float* __restrict__ scale, float* __restrict__ shift, float inv_n)
{
    int c = threadIdx.x;
    float s = 0.f, q = 0.f;
#pragma unroll
    for (int r = 0; r < REP; r++) { s += sumrep[r * 128 + c]; q += sqrep[r * 128 + c]; }
    float mean = s * inv_n;
    float var = q * inv_n - mean * mean;
    float sc = g[c] * rsqrtf(var + BN_EPS);
    scale[c] = sc;
    shift[c] = be[c] - mean * sc;
}

// ---------------- K2b: single-pass exclusive scan (1024 thr x 32 elems) -------
__global__ __launch_bounds__(1024) void k_scan(const int* __restrict__ cnt,
                                               int* __restrict__ offs,
                                               int* __restrict__ cursor)
{
    __shared__ int wsum[16];
    int t = threadIdx.x, lane = t & 63, wv = t >> 6;
    int base = t * 32;
    int v[32];
    int s = 0;
    if (base + 32 <= GSEG) {
        const int4* cp = (const int4*)(cnt + base);
#pragma unroll
        for (int j = 0; j < 8; j++) {
            int4 q = cp[j];
            v[j * 4 + 0] = q.x; v[j * 4 + 1] = q.y; v[j * 4 + 2] = q.z; v[j * 4 + 3] = q.w;
            s += q.x + q.y + q.z + q.w;
        }
    } else {
#pragma unroll
        for (int j = 0; j < 32; j++) {
            int idx = base + j;
            int x = (idx < GSEG) ? cnt[idx] : 0;
            v[j] = x; s += x;
        }
    }
    int x = s;
#pragma unroll
    for (int d = 1; d < 64; d <<= 1) {
        int u = __shfl_up(x, d, 64);
        if (lane >= d) x += u;
    }
    if (lane == 63) wsum[wv] = x;
    __syncthreads();
    if (t < 16) {
        int w = wsum[t];
#pragma unroll
        for (int d = 1; d < 16; d <<= 1) {
            int u = __shfl_up(w, d, 16);
            if (t >= d) w += u;
        }
        wsum[t] = w;
    }
    __syncthreads();
    int run = (wv ? wsum[wv - 1] : 0) + (x - s);
#pragma unroll
    for (int j = 0; j < 32; j++) {
        int idx = base + j;
        if (idx < GSEG) { offs[idx] = run; cursor[idx] = run; }
        run += v[j];
    }
    if (t == 1023) offs[GSEG] = wsum[15];
}

// ---------------- K2c: scatter 16B records {row, floor(xyz)} into seg order ----
// Widening the 4B order write to a 16B record costs nothing extra in line-RMW
// (a 4B random store already dirties the full line) and converts segsum's
// random 12B xyz gathers (~45MB of line fills) into coalesced float4 reads.
__global__ __launch_bounds__(256) void k_scatter_idx(const int* __restrict__ unq,
                                                     const float* __restrict__ xyz,
                                                     int* __restrict__ cursor,
                                                     float* __restrict__ ordrec, int n)
{
    int i = blockIdx.x * 256 + threadIdx.x;
    if (i < n) {
        float2 xy = *(const float2*)(xyz + i * 3);
        float z = xyz[i * 3 + 2];
        int pos = atomicAdd(&cursor[unq[i]], 1);
        float4 rec;
        rec.x = __int_as_float(i);
        rec.y = floorf(xy.x);
        rec.z = floorf(xy.y);
        rec.w = floorf(z);
        *(float4*)(ordrec + (size_t)pos * 4) = rec;
    }
}

// ---------------- K2d: per-segment gather sum + fused BN2 raw moments ----------
// feat_add[s][c] = acc = sum pw1*fe ; BN2 stats via P1 = sum pw2*fe, P2 = sum (pw2*fe)^2:
//   sum out = P1 - m*acc ; sum out^2 = P2 - 2*acc*P1 + m*acc^2
__global__ __launch_bounds__(256) void k_segsum(
    const u16* __restrict__ lin, const float* __restrict__ ordrec,
    const int* __restrict__ offs,
    const float* __restrict__ scale1, const float* __restrict__ shift1,
    const float* __restrict__ Wp1, const float* __restrict__ bp1,
    const float* __restrict__ Wp2, const float* __restrict__ bp2,
    float* __restrict__ feat_add, float* __restrict__ sum2rep, float* __restrict__ sumsq2rep,
    int nseg)
{
    __shared__ float sSum[128], sSq[128];
    const int t = threadIdx.x;
    if (t < 128) { sSum[t] = 0.f; sSq[t] = 0.f; }
    __syncthreads();
    const int wave = t >> 6, lane = t & 63;
    const int c = lane * 2;
    const float wa0x = Wp1[c],     wa0y = Wp1[128 + c],     wa0z = Wp1[256 + c],     ba0 = bp1[c];
    const float wa1x = Wp1[c + 1], wa1y = Wp1[128 + c + 1], wa1z = Wp1[256 + c + 1], ba1 = bp1[c + 1];
    const float wb0x = Wp2[c],     wb0y = Wp2[128 + c],     wb0z = Wp2[256 + c],     bb0 = bp2[c];
    const float wb1x = Wp2[c + 1], wb1y = Wp2[128 + c + 1], wb1z = Wp2[256 + c + 1], bb1 = bp2[c + 1];
    const float sc0 = scale1[c], sh0 = shift1[c];
    const float sc1 = scale1[c + 1], sh1 = shift1[c + 1];
    float rs0 = 0.f, rs1 = 0.f, rq0 = 0.f, rq1 = 0.f;
    const int stride = gridDim.x * 4;
    for (int s = blockIdx.x * 4 + wave; s < nseg; s += stride) {
        const int beg = offs[s], end = offs[s + 1];
        const int m = end - beg;
        // prefetch records (coalesced float4: {row, fx, fy, fz} per row)
        int rowv = 0; float fxv = 0.f, fyv = 0.f, fzv = 0.f;
        if (lane < m) {
            float4 rec = *(const float4*)(ordrec + (size_t)(beg + lane) * 4);
            rowv = __float_as_int(rec.x);
            fxv = rec.y; fyv = rec.z; fzv = rec.w;
        }
        float acc0 = 0.f, acc1 = 0.f, p10 = 0.f, p11 = 0.f, p20 = 0.f, p21 = 0.f;
        const int mm = m < 64 ? m : 64;
        int j = 0;
        // 4-row unroll: four independent 256B gathers in flight
        for (; j + 4 <= mm; j += 4) {
            int   rw[4]; float px[4], py[4], pz[4]; u32 ll[4];
#pragma unroll
            for (int k = 0; k < 4; k++) {
                rw[k] = __shfl(rowv, j + k, 64);
                px[k] = __shfl(fxv, j + k, 64);
                py[k] = __shfl(fyv, j + k, 64);
                pz[k] = __shfl(fzv, j + k, 64);
            }
#pragma unroll
            for (int k = 0; k < 4; k++)
                ll[k] = *(const u32*)(lin + (size_t)rw[k] * 128 + c);
#pragma unroll
            for (int k = 0; k < 4; k++) {
                float fe0 = fmaf(__uint_as_float(ll[k] << 16), sc0, sh0);
                float fe1 = fmaf(__uint_as_float(ll[k] & 0xffff0000u), sc1, sh1);
                float pa0 = fmaf(px[k], wa0x, fmaf(py[k], wa0y, fmaf(pz[k], wa0z, ba0)));
                float pa1 = fmaf(px[k], wa1x, fmaf(py[k], wa1y, fmaf(pz[k], wa1z, ba1)));
                float pb0 = fmaf(px[k], wb0x, fmaf(py[k], wb0y, fmaf(pz[k], wb0z, bb0)));
                float pb1 = fmaf(px[k], wb1x, fmaf(py[k], wb1y, fmaf(pz[k], wb1z, bb1)));
                acc0 = fmaf(pa0, fe0, acc0);
                acc1 = fmaf(pa1, fe1, acc1);
                float t0 = pb0 * fe0, t1 = pb1 * fe1;
                p10 += t0; p11 += t1;
                p20 = fmaf(t0, t0, p20); p21 = fmaf(t1, t1, p21);
            }
        }
        for (; j < mm; j++) {
            int row = __shfl(rowv, j, 64);
            float px = __shfl(fxv, j, 64);
            float py = __shfl(fyv, j, 64);
            float pz = __shfl(fzv, j, 64);
            u32 l2 = *(const u32*)(lin + (size_t)row * 128 + c);
            float fe0 = fmaf(__uint_as_float(l2 << 16), sc0, sh0);
            float fe1 = fmaf(__uint_as_float(l2 & 0xffff0000u), sc1, sh1);
            float pa0 = fmaf(px, wa0x, fmaf(py, wa0y, fmaf(pz, wa0z, ba0)));
            float pa1 = fmaf(px, wa1x, fmaf(py, wa1y, fmaf(pz, wa1z, ba1)));
            float pb0 = fmaf(px, wb0x, fmaf(py, wb0y, fmaf(pz, wb0z, bb0)));
            float pb1 = fmaf(px, wb1x, fmaf(py, wb1y, fmaf(pz, wb1z, bb1)));
            acc0 = fmaf(pa0, fe0, acc0);
            acc1 = fmaf(pa1, fe1, acc1);
            float t0 = pb0 * fe0, t1 = pb1 * fe1;
            p10 += t0; p11 += t1;
            p20 = fmaf(t0, t0, p20); p21 = fmaf(t1, t1, p21);
        }
        for (int jj = 64; jj < m; jj++) {   // vanishingly rare (m>64 ~ 14 sigma)
            float4 rec = *(const float4*)(ordrec + (size_t)(beg + jj) * 4);
            int row = __float_as_int(rec.x);
            float px = rec.y, py = rec.z, pz = rec.w;
            u32 l2 = *(const u32*)(lin + (size_t)row * 128 + c);
            float fe0 = fmaf(__uint_as_float(l2 << 16), sc0, sh0);
            float fe1 = fmaf(__uint_as_float(l2 & 0xffff0000u), sc1, sh1);
            float pa0 = fmaf(px, wa0x, fmaf(py, wa0y, fmaf(pz, wa0z, ba0)));
            float pa1 = fmaf(px, wa1x, fmaf(py, wa1y, fmaf(pz, wa1z, ba1)));
            float pb0 = fmaf(px, wb0x, fmaf(py, wb0y, fmaf(pz, wb0z, bb0)));
            float pb1 = fmaf(px, wb1x, fmaf(py, wb1y, fmaf(pz, wb1z, bb1)));
            acc0 = fmaf(pa0, fe0, acc0);
            acc1 = fmaf(pa1, fe1, acc1);
            float t0 = pb0 * fe0, t1 = pb1 * fe1;
            p10 += t0; p11 += t1;
            p20 = fmaf(t0, t0, p20); p21 = fmaf(t1, t1, p21);
        }
        float2 st; st.x = acc0; st.y = acc1;
        *(float2*)(feat_add + (size_t)s * 128 + c) = st;
        float fm = (float)m;
        rs0 += p10 - fm * acc0;
        rs1 += p11 - fm * acc1;
        rq0 += fmaf(fm * acc0, acc0, p20 - 2.f * acc0 * p10);
        rq1 += fmaf(fm * acc1, acc1, p21 - 2.f * acc1 * p11);
    }
    atomicAdd(&sSum[c], rs0); atomicAdd(&sSum[c + 1], rs1);
    atomicAdd(&sSq[c], rq0);  atomicAdd(&sSq[c + 1], rq1);
    __syncthreads();
    if (t < 128) {
        int rep = (blockIdx.x & (REP - 1)) * 128;
        atomicAdd(&sum2rep[rep + t], sSum[t]);
        atomicAdd(&sumsq2rep[rep + t], sSq[t]);
    }
}

// ---------------- K4: final out = relu(bn2(out_pre)) ---- (16 thr/row form) -----
__global__ __launch_bounds__(256) void k_final(
    const u16* __restrict__ lin, const float* __restrict__ xyz, const int* __restrict__ unq,
    const float* __restrict__ scale1, const float* __restrict__ shift1,
    const float* __restrict__ Wp2, const float* __restrict__ bp2,
    const float* __restrict__ feat_add,
    const float* __restrict__ scale2, const float* __restrict__ shift2,
    float* __restrict__ out, int n)
{
    __shared__ float sS[128], sH[128], sW3[384], sB[128], sS2[128], sH2[128];
    int t = threadIdx.x;
    if (t < 128) {
        sS[t] = scale1[t]; sH[t] = shift1[t]; sB[t] = bp2[t];
        sW3[t] = Wp2[t]; sW3[128 + t] = Wp2[128 + t]; sW3[256 + t] = Wp2[256 + t];
        sS2[t] = scale2[t]; sH2[t] = shift2[t];
    }
    __syncthreads();
    int row = blockIdx.x * 16 + (t >> 4);
    if (row >= n) return;
    int c0 = (t & 15) * 8;
    uint4 l8 = *(const uint4*)(lin + (size_t)row * 128 + c0);
    float f[8];
    unpack8(l8, f);
    float px = floorf(xyz[row * 3 + 0]);
    float py = floorf(xyz[row * 3 + 1]);
    float pz = floorf(xyz[row * 3 + 2]);
    int g = unq[row];
    const float4* fa = (const float4*)(feat_add + (size_t)g * 128 + c0);
    float4 fa0 = fa[0], fa1 = fa[1];
    float fav[8] = {fa0.x, fa0.y, fa0.z, fa0.w, fa1.x, fa1.y, fa1.z, fa1.w};
    float o[8];
#pragma unroll
    for (int j = 0; j < 8; j++) {
        int c = c0 + j;
        float fe = fmaf(f[j], sS[c], sH[c]);
        float pw = fmaf(px, sW3[c], fmaf(py, sW3[128 + c], fmaf(pz, sW3[256 + c], sB[c])));
        float v = pw * fe - fav[j];
        v = fmaf(v, sS2[c], sH2[c]);
        o[j] = v > 0.f ? v : 0.f;
    }
    float4 s0, s1;
    s0.x = o[0]; s0.y = o[1]; s0.z = o[2]; s0.w = o[3];
    s1.x = o[4]; s1.y = o[5]; s1.z = o[6]; s1.w = o[7];
    float* op = out + (size_t)row * 128 + c0;
    *(float4*)op = s0;
    *(float4*)(op + 4) = s1;
}

extern "C" void kernel_launch(void* const* d_in, const int* in_sizes, int n_in,
                              void* d_out, int out_size, void* d_ws, size_t ws_size,
                              hipStream_t stream)
{
    const float* xyz      = (const float*)d_in[0];
    const float* feat_all = (const float*)d_in[1];
    const int*   unq      = (const int*)d_in[2];
    const float* W_pre    = (const float*)d_in[3];
    const float* b_pre    = (const float*)d_in[4];
    const float* g1       = (const float*)d_in[5];
    const float* be1      = (const float*)d_in[6];
    const float* Wp1      = (const float*)d_in[7];
    const float* bp1      = (const float*)d_in[8];
    const float* Wp2      = (const float*)d_in[9];
    const float* bp2      = (const float*)d_in[10];
    const float* g2       = (const float*)d_in[11];
    const float* be2      = (const float*)d_in[12];
    (void)n_in; (void)out_size; (void)ws_size;

    const int n = in_sizes[0] / 3;   // 400000

    char* ws = (char*)d_ws;
    // ---- workspace layout (aliases noted) ----
    float* sum1rep   = (float*)(ws + 0);        // [REP][128] = 16384 B
    float* sumsq1rep = (float*)(ws + 16384);    // 16384 B
    float* sum2rep   = (float*)(ws + 32768);    // 16384 B
    float* sumsq2rep = (float*)(ws + 49152);    // 16384 B
    float* scale1    = (float*)(ws + 65536);
    float* shift1    = (float*)(ws + 66048);
    float* scale2    = (float*)(ws + 66560);
    float* shift2    = (float*)(ws + 67072);    // ends 67584
    int*   offs      = (int*)(ws + 67584);      // 30001 ints, ends 187588
    int*   cursor    = (int*)(ws + 187648);     // 30000 ints, ends 307648
    u16*   wt_f      = (u16*)(ws + 187648);     // 32768 B, ALIASES cursor (dead until k_scan)
    float* ordrec    = (float*)(ws + 307648);   // 400000 x 16B records, ends 6707648
    int*   cnt       = (int*)(ws + 307648);     // 30000 ints, ALIASES ordrec (dead after k_scan)
    float* feat_add  = (float*)(ws + 6707712);  // 15360000 B, ends 22067712
    u16*   lin       = (u16*)(ws + 22067712);   // 102400000 B, ends 124467712

    hipMemsetAsync(ws, 0, 65536, stream);                 // replica stats
    hipMemsetAsync(ws + 307648, 0, 120000, stream);       // cnt

    k_prep_w<<<1, 512, 0, stream>>>(W_pre, wt_f);
    k_gemm_bn1<<<(n + 511) / 512, 512, 0, stream>>>(feat_all, wt_f, b_pre, unq, cnt,
                                                    lin, sum1rep, sumsq1rep, n);
    k_fin<<<1, 128, 0, stream>>>(sum1rep, sumsq1rep, g1, be1, scale1, shift1, 1.0f / n);

    k_scan<<<1, 1024, 0, stream>>>(cnt, offs, cursor);
    k_scatter_idx<<<(n + 255) / 256, 256, 0, stream>>>(unq, xyz, cursor, ordrec, n);
    k_segsum<<<1876, 256, 0, stream>>>(lin, ordrec, offs, scale1, shift1,
                                       Wp1, bp1, Wp2, bp2, feat_add, sum2rep, sumsq2rep, GSEG);
    k_fin<<<1, 128, 0, stream>>>(sum2rep, sumsq2rep, g2, be2, scale2, shift2, 1.0f / n);
    k_final<<<(n + 15) / 16, 256, 0, stream>>>(lin, xyz, unq, scale1, shift1, Wp2, bp2,
                                               feat_add, scale2, shift2, (float*)d_out, n);
}